// Round 2
// baseline (4351.704 us; speedup 1.0000x reference)
//
#include <hip/hip_runtime.h>
#include <hip/hip_bf16.h>

#define BSZ    256
#define SEQT   2048
#define NVOCAB 10
#define DEMB   32
#define HID    64
#define G4     256   // 4*HID
#define WIN    32    // MLP token window

typedef unsigned short u16;

// ws layout (floats) — everything converted to fp32 by init_kernel
#define FLAG_OFF 0                       // 1.0 if inputs are bf16, 0.0 if fp32
#define XZ_OFF   1                       // 10*256 = 2560
#define WH_OFF   (XZ_OFF + NVOCAB * G4)  // 64*256 = 16384
#define W1_OFF   (WH_OFF + HID * G4)     // 128*64 = 8192
#define W2_OFF   (W1_OFF + 128 * 64)     // 64*32  = 2048
#define W3_OFF   (W2_OFF + 64 * 32)      // 32*10  = 320
#define B1_OFF   (W3_OFF + 32 * NVOCAB)  // 64
#define B2_OFF   (B1_OFF + 64)           // 32
#define B3_OFF   (B2_OFF + 32)           // 10
// total ≈ 29611 floats ≈ 116 KB

__device__ __forceinline__ float bf2f(u16 x) {
    union { unsigned int u; float f; } v; v.u = ((unsigned int)x) << 16; return v.f;
}
__device__ __forceinline__ u16 f2bf(float f) {
    union { float f; unsigned int u; } v; v.f = f;
    unsigned int r = v.u + 0x7fff + ((v.u >> 16) & 1);   // RNE
    return (u16)(r >> 16);
}
// dtype-flexible weight read: element i of a tensor that is either bf16 or fp32
__device__ __forceinline__ float ldw(const void* p, int i, bool isbf) {
    return isbf ? bf2f(((const u16*)p)[i]) : ((const float*)p)[i];
}
__device__ __forceinline__ float fsig(float x) {
    x = fminf(fmaxf(x, -30.f), 30.f);
    return 1.f / (1.f + __expf(-x));
}
__device__ __forceinline__ float ftanh(float x) {
    x = fminf(fmaxf(x, -15.f), 15.f);
    float e = __expf(2.f * x);
    return (e - 1.f) / (e + 1.f);
}

// One-time per-call prep: detect input dtype, build xz table (E@Wx+b has only
// 10 distinct rows!), convert all weights to fp32 in ws.
__global__ void init_kernel(const void* __restrict__ E,  const void* __restrict__ Wx,
                            const void* __restrict__ Wh, const void* __restrict__ bg,
                            const void* __restrict__ W1, const void* __restrict__ b1,
                            const void* __restrict__ W2, const void* __restrict__ b2,
                            const void* __restrict__ W3, const void* __restrict__ b3,
                            float* __restrict__ ws) {
    __shared__ int s_isbf;
    const int tid = threadIdx.x;  // 256 threads, 1 block
    if (tid == 0) s_isbf = 1;
    __syncthreads();
    // Detect: if E's buffer is bf16, all 320 u16 decode to |v| < 16 (E ~ 0.05
    // scale). If it's fp32, the low-halves decode to random exponents and at
    // least one exceeds 16 with overwhelming probability.
    {
        const u16* Eu = (const u16*)E;
        for (int i = tid; i < NVOCAB * DEMB; i += 256) {
            float v = bf2f(Eu[i]);
            if (!(fabsf(v) < 16.0f)) s_isbf = 0;   // benign race, all write 0
        }
    }
    __syncthreads();
    const bool isbf = (s_isbf != 0);
    if (tid == 0) ws[FLAG_OFF] = isbf ? 1.0f : 0.0f;

    // xz[v][g] = b[g] + sum_d E[v][d] * Wx[d][g]
    {
        const int g = tid;
        for (int v = 0; v < NVOCAB; v++) {
            float acc = ldw(bg, g, isbf);
            #pragma unroll
            for (int d = 0; d < DEMB; d++)
                acc += ldw(E, v * DEMB + d, isbf) * ldw(Wx, d * G4 + g, isbf);
            ws[XZ_OFF + v * G4 + g] = acc;
        }
    }
    for (int i = tid; i < HID * G4;     i += 256) ws[WH_OFF + i] = ldw(Wh, i, isbf);
    for (int i = tid; i < 128 * 64;     i += 256) ws[W1_OFF + i] = ldw(W1, i, isbf);
    for (int i = tid; i < 64 * 32;      i += 256) ws[W2_OFF + i] = ldw(W2, i, isbf);
    for (int i = tid; i < 32 * NVOCAB;  i += 256) ws[W3_OFF + i] = ldw(W3, i, isbf);
    if (tid < 64)     ws[B1_OFF + tid] = ldw(b1, tid, isbf);
    if (tid < 32)     ws[B2_OFF + tid] = ldw(b2, tid, isbf);
    if (tid < NVOCAB) ws[B3_OFF + tid] = ldw(b3, tid, isbf);
}

// One block per batch element; both LSTM chains + fused MLP head.
// tid in [0,512): s = tid>>8 (which sequence), g = tid&255 (gate column)
__global__ __launch_bounds__(512, 2) void lstm_fused(
    const int* __restrict__ num1, const int* __restrict__ num2,
    const float* __restrict__ ws, void* __restrict__ outv)
{
    __shared__ float xz_s[NVOCAB * G4];                 // 10 KB
    __shared__ __align__(16) float hwin[WIN][2 * HID];  // 16 KB ring of h (both chains)
    __shared__ float zbuf[512];                          // 2 KB
    __shared__ __align__(16) float w1buf[WIN][64];       // 8 KB
    __shared__ float w2buf[WIN][33];                     // padded

    const int tid = threadIdx.x;
    const int b   = blockIdx.x;
    const int s   = tid >> 8;
    const int g   = tid & 255;
    const bool outbf = (ws[FLAG_OFF] != 0.0f);          // uniform branch

    for (int i = tid; i < NVOCAB * G4; i += 512) xz_s[i] = ws[XZ_OFF + i];

    // Wh column g resident in 64 VGPRs (fp32 from ws)
    float wh[HID];
    #pragma unroll
    for (int k = 0; k < HID; k++) wh[k] = ws[WH_OFF + k * G4 + g];

    if (tid < 128) hwin[WIN - 1][tid] = 0.f;  // h_{-1} = 0 lives in row WIN-1

    const int*   nums = (s == 0 ? num1 : num2) + b * SEQT;
    const float* W1f  = ws + W1_OFF;
    const float* W2f  = ws + W2_OFF;
    const float* W3f  = ws + W3_OFF;

    float c = 0.f;  // cell state (meaningful for tid<128)
    __syncthreads();

    int idx = nums[0];
    for (int t = 0; t < SEQT; t++) {
        int nidx = (t + 1 < SEQT) ? nums[t + 1] : 0;  // prefetch off critical path

        // Phase 1: z[g] = xz[idx][g] + Wh[:,g] . h_prev   (all 512 threads)
        const float* hp = &hwin[(t + WIN - 1) & (WIN - 1)][s * HID];
        float acc = 0.f;
        #pragma unroll
        for (int k = 0; k < HID; k += 4) {
            float4 h4 = *(const float4*)(hp + k);   // ds_read_b128, wave-broadcast
            acc += wh[k] * h4.x + wh[k + 1] * h4.y + wh[k + 2] * h4.z + wh[k + 3] * h4.w;
        }
        zbuf[tid] = acc + xz_s[idx * G4 + g];
        idx = nidx;
        __syncthreads();

        // Phase 2: gates + state update (threads 0..127 = (chain, unit))
        if (tid < 128) {
            const int ss = tid >> 6, j = tid & 63;
            const float* zz = &zbuf[ss * G4];
            float ig = fsig(zz[j]);            // Keras gate order: i, f, c, o
            float fg = fsig(zz[64 + j]);
            float gg = ftanh(zz[128 + j]);
            float og = fsig(zz[192 + j]);
            c = fg * c + ig * gg;
            hwin[t & (WIN - 1)][ss * HID + j] = og * ftanh(c);
        }
        __syncthreads();

        // Every WIN steps: MLP head on the buffered tokens (all 512 threads)
        if ((t & (WIN - 1)) == (WIN - 1)) {
            const int t0 = t - (WIN - 1);
            {   // layer 1: [WIN,128] @ [128,64], 4 tokens per thread
                const int o1 = tid & 63, tk = tid >> 6;
                float a0 = ws[B1_OFF + o1], a1 = a0, a2 = a0, a3 = a0;
                for (int k = 0; k < 128; k += 4) {
                    float4 h0 = *(const float4*)&hwin[tk][k];
                    float4 h1 = *(const float4*)&hwin[tk + 8][k];
                    float4 h2 = *(const float4*)&hwin[tk + 16][k];
                    float4 h3 = *(const float4*)&hwin[tk + 24][k];
                    float w0 = W1f[k * 64 + o1];
                    float w1 = W1f[(k + 1) * 64 + o1];
                    float w2 = W1f[(k + 2) * 64 + o1];
                    float w3 = W1f[(k + 3) * 64 + o1];
                    a0 += w0 * h0.x + w1 * h0.y + w2 * h0.z + w3 * h0.w;
                    a1 += w0 * h1.x + w1 * h1.y + w2 * h1.z + w3 * h1.w;
                    a2 += w0 * h2.x + w1 * h2.y + w2 * h2.z + w3 * h2.w;
                    a3 += w0 * h3.x + w1 * h3.y + w2 * h3.z + w3 * h3.w;
                }
                w1buf[tk][o1]      = fmaxf(a0, 0.f);
                w1buf[tk + 8][o1]  = fmaxf(a1, 0.f);
                w1buf[tk + 16][o1] = fmaxf(a2, 0.f);
                w1buf[tk + 24][o1] = fmaxf(a3, 0.f);
            }
            __syncthreads();
            {   // layer 2: [WIN,64] @ [64,32], 2 tokens per thread
                const int o2 = tid & 31, tk = tid >> 5;
                float a0 = ws[B2_OFF + o2], a1 = a0;
                for (int k = 0; k < 64; k += 4) {
                    float4 h0 = *(const float4*)&w1buf[tk][k];
                    float4 h1 = *(const float4*)&w1buf[tk + 16][k];
                    float w0 = W2f[k * 32 + o2];
                    float w1 = W2f[(k + 1) * 32 + o2];
                    float w2 = W2f[(k + 2) * 32 + o2];
                    float w3 = W2f[(k + 3) * 32 + o2];
                    a0 += w0 * h0.x + w1 * h0.y + w2 * h0.z + w3 * h0.w;
                    a1 += w0 * h1.x + w1 * h1.y + w2 * h1.z + w3 * h1.w;
                }
                w2buf[tk][o2]      = fmaxf(a0, 0.f);
                w2buf[tk + 16][o2] = fmaxf(a1, 0.f);
            }
            __syncthreads();
            // layer 3: [WIN,32] @ [32,10] -> output (dtype per detected flag)
            if (tid < WIN * NVOCAB) {
                const int o3 = tid % NVOCAB, tk = tid / NVOCAB;
                float a = ws[B3_OFF + o3];
                #pragma unroll
                for (int k = 0; k < 32; k++)
                    a += W3f[k * NVOCAB + o3] * w2buf[tk][k];
                const size_t oi = (size_t)(b * SEQT + t0 + tk) * NVOCAB + o3;
                if (outbf) ((u16*)outv)[oi] = f2bf(a);
                else       ((float*)outv)[oi] = a;
            }
            __syncthreads();
        }
    }
}

extern "C" void kernel_launch(void* const* d_in, const int* in_sizes, int n_in,
                              void* d_out, int out_size, void* d_ws, size_t ws_size,
                              hipStream_t stream) {
    const int* num1 = (const int*)d_in[0];
    const int* num2 = (const int*)d_in[1];
    float* ws = (float*)d_ws;

    hipLaunchKernelGGL(init_kernel, dim3(1), dim3(256), 0, stream,
                       d_in[2], d_in[3], d_in[4], d_in[5], d_in[6], d_in[7],
                       d_in[8], d_in[9], d_in[10], d_in[11], ws);
    hipLaunchKernelGGL(lstm_fused, dim3(BSZ), dim3(512), 0, stream,
                       num1, num2, ws, d_out);
}

// Round 3
// 1412.192 us; speedup vs baseline: 3.0815x; 3.0815x over previous
//
#include <hip/hip_runtime.h>
#include <hip/hip_bf16.h>
#include <hip/hip_fp16.h>

#define BSZ    256
#define SEQT   2048
#define NVOCAB 10
#define DEMB   32
#define HID    64
#define G4     256   // 4*HID
#define WIN    32    // MLP token window

typedef unsigned short u16;
typedef unsigned int   u32;

// ws layout (floats) — everything converted to fp32 by init_kernel
#define FLAG_OFF 0                       // 1.0 if inputs are bf16, 0.0 if fp32
#define XZ_OFF   1                       // 10*256
#define WH_OFF   (XZ_OFF + NVOCAB * G4)  // 64*256
#define W1_OFF   (WH_OFF + HID * G4)     // 128*64
#define W2_OFF   (W1_OFF + 128 * 64)     // 64*32
#define W3_OFF   (W2_OFF + 64 * 32)      // 32*10
#define B1_OFF   (W3_OFF + 32 * NVOCAB)  // 64
#define B2_OFF   (B1_OFF + 64)           // 32
#define B3_OFF   (B2_OFF + 32)           // 10

__device__ __forceinline__ float bf2f(u16 x) {
    union { u32 u; float f; } v; v.u = ((u32)x) << 16; return v.f;
}
__device__ __forceinline__ u16 f2bf(float f) {
    union { float f; u32 u; } v; v.f = f;
    u32 r = v.u + 0x7fff + ((v.u >> 16) & 1);   // RNE
    return (u16)(r >> 16);
}
__device__ __forceinline__ float ldw(const void* p, int i, bool isbf) {
    return isbf ? bf2f(((const u16*)p)[i]) : ((const float*)p)[i];
}
__device__ __forceinline__ float frcp(float x) { return __builtin_amdgcn_rcpf(x); }

// quad-lane DPP helpers (VALU-rate cross-lane within groups of 4)
__device__ __forceinline__ float qswap1(float x) {  // quad_perm [1,0,3,2]
    return __int_as_float(__builtin_amdgcn_mov_dpp(__float_as_int(x), 0xB1, 0xF, 0xF, true));
}
__device__ __forceinline__ float qswap2(float x) {  // quad_perm [2,3,0,1]
    return __int_as_float(__builtin_amdgcn_mov_dpp(__float_as_int(x), 0x4E, 0xF, 0xF, true));
}
template <int K>
__device__ __forceinline__ float qbcast(float x) {  // quad_perm [K,K,K,K]
    return __int_as_float(__builtin_amdgcn_mov_dpp(__float_as_int(x), K * 0x55, 0xF, 0xF, true));
}

// One-time prep: detect dtype, build xz table (E@Wx+b, only 10 rows), fp32 weights.
__global__ void init_kernel(const void* __restrict__ E,  const void* __restrict__ Wx,
                            const void* __restrict__ Wh, const void* __restrict__ bg,
                            const void* __restrict__ W1, const void* __restrict__ b1,
                            const void* __restrict__ W2, const void* __restrict__ b2,
                            const void* __restrict__ W3, const void* __restrict__ b3,
                            float* __restrict__ ws) {
    __shared__ int s_isbf;
    const int tid = threadIdx.x;  // 256 threads, 1 block
    if (tid == 0) s_isbf = 1;
    __syncthreads();
    {   // bf16 data decodes to small values; fp32 low-halves decode to wild exponents
        const u16* Eu = (const u16*)E;
        for (int i = tid; i < NVOCAB * DEMB; i += 256) {
            float v = bf2f(Eu[i]);
            if (!(fabsf(v) < 16.0f)) s_isbf = 0;
        }
    }
    __syncthreads();
    const bool isbf = (s_isbf != 0);
    if (tid == 0) ws[FLAG_OFF] = isbf ? 1.0f : 0.0f;

    {   // xz[v][g] = b[g] + sum_d E[v][d] * Wx[d][g]
        const int g = tid;
        for (int v = 0; v < NVOCAB; v++) {
            float acc = ldw(bg, g, isbf);
            #pragma unroll
            for (int d = 0; d < DEMB; d++)
                acc += ldw(E, v * DEMB + d, isbf) * ldw(Wx, d * G4 + g, isbf);
            ws[XZ_OFF + v * G4 + g] = acc;
        }
    }
    for (int i = tid; i < HID * G4;    i += 256) ws[WH_OFF + i] = ldw(Wh, i, isbf);
    for (int i = tid; i < 128 * 64;    i += 256) ws[W1_OFF + i] = ldw(W1, i, isbf);
    for (int i = tid; i < 64 * 32;     i += 256) ws[W2_OFF + i] = ldw(W2, i, isbf);
    for (int i = tid; i < 32 * NVOCAB; i += 256) ws[W3_OFF + i] = ldw(W3, i, isbf);
    if (tid < 64)     ws[B1_OFF + tid] = ldw(b1, tid, isbf);
    if (tid < 32)     ws[B2_OFF + tid] = ldw(b2, tid, isbf);
    if (tid < NVOCAB) ws[B3_OFF + tid] = ldw(b3, tid, isbf);
}

// One block per batch element. tid = ss*256 + j*4 + p:
//   ss = chain (0/1), j = LSTM unit (0..63), p = k-part AND gate index (0..3).
// Per step: each thread accumulates 4 gate partials of unit j over k in
// [16p,16p+16), quad-DPP butterfly reduces over p, lane p activates gate p,
// quad-broadcast, redundant c/h update -> ONE barrier per step.
__global__ __launch_bounds__(512, 2) void lstm_fused(
    const int* __restrict__ num1, const int* __restrict__ num2,
    const float* __restrict__ ws, void* __restrict__ outv)
{
    __shared__ float xzT[4][NVOCAB * 64 + 8];       // per-gate, skewed (+8) = 10368 B
    __shared__ __align__(16) float hwin[WIN][128];  // 16384 B  h ring, both chains
    __shared__ u32   W1p[64 * 64];                  // 16384 B  f16-pair packed [kpair][o1]
    __shared__ u32   W2p[32 * 32];                  //  4096 B  [kpair][o2]
    __shared__ float W3s[32 * NVOCAB];              //  1280 B
    __shared__ float b1s[64], b2s[32], b3s[16];
    __shared__ __align__(16) float w1buf[WIN][64];  //  8192 B
    __shared__ float w2buf[WIN][33];                //  4224 B (padded)
    __shared__ int   idxbuf[2][WIN];                //   256 B

    const int tid = threadIdx.x;
    const int bb  = blockIdx.x;
    const int ss  = tid >> 8;
    const int r   = tid & 255;
    const int j   = r >> 2;
    const int p   = r & 3;
    const int p16 = p << 4;
    const bool outbf = (ws[FLAG_OFF] != 0.0f);

    // ---- stage constants into LDS ----
    for (int i = tid; i < 4 * NVOCAB * 64; i += 512) {
        int pg = i / (NVOCAB * 64), rr = i % (NVOCAB * 64);
        int v = rr >> 6, jj = rr & 63;
        xzT[pg][v * 64 + jj] = ws[XZ_OFF + v * G4 + pg * 64 + jj];
    }
    for (int i = tid; i < 64 * 64; i += 512) {      // W1 [128][64] -> f16 pairs over k
        int kk = i >> 6, o1 = i & 63;
        float2 f2 = make_float2(ws[W1_OFF + (2 * kk) * 64 + o1],
                                ws[W1_OFF + (2 * kk + 1) * 64 + o1]);
        union { __half2 h; u32 u; } cv; cv.h = __float22half2_rn(f2);
        W1p[i] = cv.u;
    }
    for (int i = tid; i < 32 * 32; i += 512) {      // W2 [64][32] -> f16 pairs over k
        int kk = i >> 5, o2 = i & 31;
        float2 f2 = make_float2(ws[W2_OFF + (2 * kk) * 32 + o2],
                                ws[W2_OFF + (2 * kk + 1) * 32 + o2]);
        union { __half2 h; u32 u; } cv; cv.h = __float22half2_rn(f2);
        W2p[i] = cv.u;
    }
    for (int i = tid; i < 32 * NVOCAB; i += 512) W3s[i] = ws[W3_OFF + i];
    if (tid < 64) b1s[tid] = ws[B1_OFF + tid];
    if (tid < 32) b2s[tid] = ws[B2_OFF + tid];
    if (tid < NVOCAB) b3s[tid] = ws[B3_OFF + tid];
    if (tid < 128) hwin[WIN - 1][tid] = 0.f;        // h_{-1} = 0
    if (tid < 64) {                                  // first index window
        int c0 = tid >> 5, tt = tid & 31;
        const int* np = (c0 == 0 ? num1 : num2) + bb * SEQT;
        idxbuf[c0][tt] = np[tt];
    }

    // Wh fragment: whr[gate*16 + kk] = Wh[16p+kk][gate*64 + j]
    float whr[64];
    #pragma unroll
    for (int g = 0; g < 4; g++)
        #pragma unroll
        for (int kk = 0; kk < 16; kk++)
            whr[g * 16 + kk] = ws[WH_OFF + (p16 + kk) * G4 + g * 64 + j];

    const float selg = (p == 2) ? 2.f : 1.f;  // tanh(z) = 2*sigmoid(2z)-1
    float c = 0.f;
    __syncthreads();

    for (int t = 0; t < SEQT; t++) {
        const int tw   = t & (WIN - 1);
        const int prow = (t + WIN - 1) & (WIN - 1);

        const int idx = idxbuf[ss][tw];
        const float xzv = xzT[p][idx * 64 + j];     // this lane's gate bias term

        // matvec partials: 4 gates x 16 k's
        const float4* hp4 = (const float4*)&hwin[prow][ss * 64 + p16];
        float hv[16];
        *(float4*)&hv[0]  = hp4[0];
        *(float4*)&hv[4]  = hp4[1];
        *(float4*)&hv[8]  = hp4[2];
        *(float4*)&hv[12] = hp4[3];
        float ai = 0.f, af = 0.f, ag = 0.f, ao = 0.f;
        #pragma unroll
        for (int kk = 0; kk < 16; kk++) {
            const float h = hv[kk];
            ai += whr[kk]      * h;
            af += whr[16 + kk] * h;
            ag += whr[32 + kk] * h;
            ao += whr[48 + kk] * h;
        }
        // quad butterfly reduce over p (all lanes get full sums)
        ai += qswap1(ai); ai += qswap2(ai);
        af += qswap1(af); af += qswap2(af);
        ag += qswap1(ag); ag += qswap2(ag);
        ao += qswap1(ao); ao += qswap2(ao);

        // lane p activates gate p
        float z = (p == 0) ? ai : (p == 1) ? af : (p == 2) ? ag : ao;
        z += xzv;
        float za = fminf(fmaxf(selg * z, -30.f), 30.f);
        float sg = frcp(1.f + __expf(-za));
        float y  = selg * sg - (selg - 1.f);

        const float gi = qbcast<0>(y);
        const float gf = qbcast<1>(y);
        const float gg = qbcast<2>(y);
        const float go = qbcast<3>(y);
        c = gf * c + gi * gg;
        float cc = fminf(fmaxf(c, -15.f), 15.f);
        float e  = __expf(2.f * cc);
        float hval = go * ((e - 1.f) * frcp(e + 1.f));
        if (p == 0) hwin[tw][ss * 64 + j] = hval;
        __syncthreads();

        // ---- every WIN steps: fused MLP head on buffered tokens ----
        if (tw == WIN - 1) {
            const int t0 = t - (WIN - 1);
            if (tid < 64) {   // refill next index window (latency hidden by layer 1)
                int c0 = tid >> 5, tt = tid & 31;
                int tn = t + 1 + tt;
                const int* np = (c0 == 0 ? num1 : num2) + bb * SEQT;
                idxbuf[c0][tt] = (tn < SEQT) ? np[tn] : 0;
            }
            {   // layer 1: [WIN,128] @ [128,64], whole wave shares tk (broadcast reads)
                const int o1 = tid & 63, tk = tid >> 6;
                float a0 = b1s[o1], a1 = a0, a2 = a0, a3 = a0;
                #pragma unroll 4
                for (int kk = 0; kk < 64; kk += 2) {   // covers k = 2kk .. 2kk+3
                    float4 h0 = *(const float4*)&hwin[tk][2 * kk];
                    float4 h1 = *(const float4*)&hwin[tk + 8][2 * kk];
                    float4 h2 = *(const float4*)&hwin[tk + 16][2 * kk];
                    float4 h3 = *(const float4*)&hwin[tk + 24][2 * kk];
                    union { u32 u; __half2 h; } ca, cb;
                    ca.u = W1p[kk * 64 + o1];
                    cb.u = W1p[(kk + 1) * 64 + o1];
                    float2 wA = __half22float2(ca.h);
                    float2 wB = __half22float2(cb.h);
                    a0 += wA.x * h0.x + wA.y * h0.y + wB.x * h0.z + wB.y * h0.w;
                    a1 += wA.x * h1.x + wA.y * h1.y + wB.x * h1.z + wB.y * h1.w;
                    a2 += wA.x * h2.x + wA.y * h2.y + wB.x * h2.z + wB.y * h2.w;
                    a3 += wA.x * h3.x + wA.y * h3.y + wB.x * h3.z + wB.y * h3.w;
                }
                w1buf[tk][o1]      = fmaxf(a0, 0.f);
                w1buf[tk + 8][o1]  = fmaxf(a1, 0.f);
                w1buf[tk + 16][o1] = fmaxf(a2, 0.f);
                w1buf[tk + 24][o1] = fmaxf(a3, 0.f);
            }
            __syncthreads();
            {   // layer 2: [WIN,64] @ [64,32]
                const int o2 = tid & 31, tk = tid >> 5;
                float a0 = b2s[o2], a1 = a0;
                #pragma unroll 4
                for (int kk = 0; kk < 32; kk += 2) {
                    float4 h0 = *(const float4*)&w1buf[tk][2 * kk];
                    float4 h1 = *(const float4*)&w1buf[tk + 16][2 * kk];
                    union { u32 u; __half2 h; } ca, cb;
                    ca.u = W2p[kk * 32 + o2];
                    cb.u = W2p[(kk + 1) * 32 + o2];
                    float2 wA = __half22float2(ca.h);
                    float2 wB = __half22float2(cb.h);
                    a0 += wA.x * h0.x + wA.y * h0.y + wB.x * h0.z + wB.y * h0.w;
                    a1 += wA.x * h1.x + wA.y * h1.y + wB.x * h1.z + wB.y * h1.w;
                }
                w2buf[tk][o2]      = fmaxf(a0, 0.f);
                w2buf[tk + 16][o2] = fmaxf(a1, 0.f);
            }
            __syncthreads();
            // layer 3: [WIN,32] @ [32,10] -> out (coalesced: oi is contiguous in tid)
            if (tid < WIN * NVOCAB) {
                const int o3 = tid % NVOCAB, tk = tid / NVOCAB;
                float a = b3s[o3];
                #pragma unroll
                for (int k = 0; k < 32; k++)
                    a += W3s[k * NVOCAB + o3] * w2buf[tk][k];
                const size_t oi = (size_t)(bb * SEQT + t0 + tk) * NVOCAB + o3;
                if (outbf) ((u16*)outv)[oi] = f2bf(a);
                else       ((float*)outv)[oi] = a;
            }
            // no trailing barrier needed: next conflicting writes are >=32
            // step-barriers away (w2buf/w1buf), and hwin row reuse is guarded
            // by the layer-2 barrier above.
        }
    }
}

extern "C" void kernel_launch(void* const* d_in, const int* in_sizes, int n_in,
                              void* d_out, int out_size, void* d_ws, size_t ws_size,
                              hipStream_t stream) {
    const int* num1 = (const int*)d_in[0];
    const int* num2 = (const int*)d_in[1];
    float* ws = (float*)d_ws;

    hipLaunchKernelGGL(init_kernel, dim3(1), dim3(256), 0, stream,
                       d_in[2], d_in[3], d_in[4], d_in[5], d_in[6], d_in[7],
                       d_in[8], d_in[9], d_in[10], d_in[11], ws);
    hipLaunchKernelGGL(lstm_fused, dim3(BSZ), dim3(512), 0, stream,
                       num1, num2, ws, d_out);
}